// Round 3
// baseline (445.065 us; speedup 1.0000x reference)
//
#include <hip/hip_runtime.h>

typedef unsigned short u16;
typedef unsigned int u32;
typedef __bf16 bf16x8 __attribute__((ext_vector_type(8)));
typedef float f32x4 __attribute__((ext_vector_type(4)));

#define BB   4
#define TT   1024
#define CDIM 2048
#define NH   16
#define NKV  4
#define HDIM 128

__device__ __forceinline__ float b2f(u16 u) {
    union { u32 i; float f; } x; x.i = ((u32)u) << 16; return x.f;
}
__device__ __forceinline__ u16 f2b(float f) {
    union { float f; u32 i; } x; x.f = f;
    u32 r = (x.i + 0x7fffu + ((x.i >> 16) & 1u)) >> 16;
    return (u16)r;
}
__device__ __forceinline__ void async16(const void* g, void* l) {
    __builtin_amdgcn_global_load_lds((const __attribute__((address_space(1))) void*)g,
                                     (__attribute__((address_space(3))) void*)l, 16, 0, 0);
}

// ---------------------------------------------------------------------------
// Dtype probe — sample EVEN u16 indices. For fp32 data those are the LOW
// mantissa halves: reinterpreted as bf16 the exponent field is uniform ->
// ~72% implausible. For bf16 N(0,1) data they are real elements -> ~0%.
// ---------------------------------------------------------------------------
__global__ void detect_k(const u16* __restrict__ x, u32* __restrict__ flag) {
    __shared__ int cnt;
    if (threadIdx.x == 0) cnt = 0;
    __syncthreads();
    int bad = 0;
#pragma unroll
    for (int i = 0; i < 4; i++) {
        u16 v = x[(threadIdx.x * 4 + i) * 2];    // EVEN index
        int e = (v >> 7) & 0xFF;
        if (v != 0 && (e < 90 || e > 160)) bad++;
    }
    atomicAdd(&cnt, bad);
    __syncthreads();
    if (threadIdx.x == 0) *flag = (cnt > 100) ? 1u : 0u;
}

// Convert-or-copy to bf16, 4 elements per thread. n multiple of 1024.
__global__ __launch_bounds__(256) void conv_k(const void* __restrict__ src,
                                              u16* __restrict__ dst,
                                              const u32* __restrict__ flag, int n) {
    int i = blockIdx.x * 256 + threadIdx.x;
    if (i * 4 >= n) return;
    union { u16 u[4]; ushort4 v; } o;
    if (*flag) {
        float4 f = ((const float4*)src)[i];
        o.u[0] = f2b(f.x); o.u[1] = f2b(f.y); o.u[2] = f2b(f.z); o.u[3] = f2b(f.w);
    } else {
        o.v = ((const ushort4*)src)[i];
    }
    ((ushort4*)dst)[i] = o.v;
}

// ---------------------------------------------------------------------------
// Tiled transpose with dtype-flexible load: WT[c][r] = bf16(W[r][c]).
// rows, cols multiples of 64.
// ---------------------------------------------------------------------------
__global__ __launch_bounds__(256) void transpose_k(const void* __restrict__ W,
                                                   u16* __restrict__ WT,
                                                   int rows, int cols,
                                                   const u32* __restrict__ flag) {
    __shared__ alignas(16) u16 tile[64 * 65];
    const bool f32m = (*flag != 0);
    const int r0 = blockIdx.y * 64, c0 = blockIdx.x * 64;
#pragma unroll
    for (int i = 0; i < 16; i++) {
        int c = threadIdx.x + i * 256;      // 4096 elements
        int rr = c >> 6, cc = c & 63;
        long idx = (long)(r0 + rr) * cols + c0 + cc;
        tile[rr * 65 + cc] = f32m ? f2b(((const float*)W)[idx]) : ((const u16*)W)[idx];
    }
    __syncthreads();
#pragma unroll
    for (int i = 0; i < 16; i++) {
        int c = threadIdx.x + i * 256;
        int rr = c >> 6, cc = c & 63;       // out row rr (orig col), out col cc
        WT[(long)(c0 + rr) * rows + r0 + cc] = tile[cc * 65 + rr];
    }
}

// ---------------------------------------------------------------------------
// m97-style bf16 GEMM: C[m][n] = sum_k A[m][k] * Bt[n][k].
// 128x128 tile, 4 waves (2x2), BK=32, global_load_lds staging.
// Store bf16, or fp32 if (flag && *flag).
// ---------------------------------------------------------------------------
__global__ __launch_bounds__(256) void gemm_bt(const u16* __restrict__ A,
                                               const u16* __restrict__ Bt,
                                               void* __restrict__ C,
                                               int M, int N, int Kd,
                                               const u32* __restrict__ flag) {
    __shared__ alignas(16) u16 As[128 * 32];
    __shared__ alignas(16) u16 Bs[128 * 32];
    const int tid = threadIdx.x;
    const int w = tid >> 6, lane = tid & 63;
    const int wm = w >> 1, wn = w & 1;
    const int l16 = lane & 15, quad = lane >> 4;
    const int bm = blockIdx.y, bn = blockIdx.x;
    const long arow0 = (long)bm * 128;
    const long brow0 = (long)bn * 128;
    const int srow = lane >> 2;     // row within 16-row staging slab
    const int schunk = lane & 3;    // 16B chunk within row (BK=32 bf16 = 64B)

    f32x4 acc[4][4];
#pragma unroll
    for (int i = 0; i < 4; i++)
#pragma unroll
        for (int j = 0; j < 4; j++) acc[i][j] = {0.f, 0.f, 0.f, 0.f};

    for (int k0 = 0; k0 < Kd; k0 += 32) {
        __syncthreads();
#pragma unroll
        for (int j = 0; j < 2; j++) {
            int r0 = w * 32 + j * 16;
            const u16* gA = A + (arow0 + r0 + srow) * Kd + k0 + schunk * 8;
            async16(gA, &As[r0 * 32]);
            const u16* gB = Bt + (brow0 + r0 + srow) * Kd + k0 + schunk * 8;
            async16(gB, &Bs[r0 * 32]);
        }
        __syncthreads();
        bf16x8 af[4], bfr[4];
#pragma unroll
        for (int mt = 0; mt < 4; mt++)
            af[mt] = *(const bf16x8*)&As[(wm * 64 + mt * 16 + l16) * 32 + quad * 8];
#pragma unroll
        for (int nt = 0; nt < 4; nt++)
            bfr[nt] = *(const bf16x8*)&Bs[(wn * 64 + nt * 16 + l16) * 32 + quad * 8];
#pragma unroll
        for (int mt = 0; mt < 4; mt++)
#pragma unroll
            for (int nt = 0; nt < 4; nt++)
                acc[mt][nt] = __builtin_amdgcn_mfma_f32_16x16x32_bf16(
                    af[mt], bfr[nt], acc[mt][nt], 0, 0, 0);
    }
    const bool f32m = (flag != nullptr) && (*flag != 0);
#pragma unroll
    for (int mt = 0; mt < 4; mt++) {
#pragma unroll
        for (int nt = 0; nt < 4; nt++) {
            int col = bn * 128 + wn * 64 + nt * 16 + l16;
#pragma unroll
            for (int r = 0; r < 4; r++) {
                long row = bm * 128 + wm * 64 + mt * 16 + quad * 4 + r;
                if (f32m) ((float*)C)[row * N + col] = acc[mt][nt][r];
                else      ((u16*)C)[row * N + col] = f2b(acc[mt][nt][r]);
            }
        }
    }
}

// ---------------------------------------------------------------------------
// RoPE on Q: Qraw (B*T, 2048) -> Q (B,H,T,HD)
// ---------------------------------------------------------------------------
__global__ __launch_bounds__(256) void rope_q_kernel(const u16* __restrict__ Qraw,
                                                     const u16* __restrict__ cs,
                                                     const u16* __restrict__ sn,
                                                     u16* __restrict__ Q) {
    int idx = blockIdx.x * 256 + threadIdx.x;   // (b*H+h, t, d<64)
    int d = idx & 63;
    int t = (idx >> 6) & (TT - 1);
    int bh = idx >> 16;
    long src = ((long)((bh >> 4) * TT + t)) * CDIM + (bh & 15) * HDIM;
    float u1 = b2f(Qraw[src + d]), u2 = b2f(Qraw[src + d + 64]);
    float c = b2f(cs[t * 64 + d]), s = b2f(sn[t * 64 + d]);
    long dst = ((long)bh * TT + t) * HDIM;
    Q[dst + d] = f2b(u1 * c - u2 * s);
    Q[dst + d + 64] = f2b(u1 * s + u2 * c);
}

// RoPE on K: KVraw (B*T, 1024) cols [kvh*128+d] -> K (B,KVH,T,HD)
__global__ __launch_bounds__(256) void rope_k_kernel(const u16* __restrict__ KVraw,
                                                     const u16* __restrict__ cs,
                                                     const u16* __restrict__ sn,
                                                     u16* __restrict__ K) {
    int idx = blockIdx.x * 256 + threadIdx.x;   // (b*KVH+kvh, t, d<64)
    int d = idx & 63;
    int t = (idx >> 6) & (TT - 1);
    int bk = idx >> 16;
    long src = ((long)((bk >> 2) * TT + t)) * 1024 + (bk & 3) * HDIM;
    float u1 = b2f(KVraw[src + d]), u2 = b2f(KVraw[src + d + 64]);
    float c = b2f(cs[t * 64 + d]), s = b2f(sn[t * 64 + d]);
    long dst = ((long)bk * TT + t) * HDIM;
    K[dst + d] = f2b(u1 * c - u2 * s);
    K[dst + d + 64] = f2b(u1 * s + u2 * c);
}

// V rearrange: KVraw cols [512 + kvh*128 + d] -> Vt (B,KVH,HD,T)
__global__ __launch_bounds__(256) void vt_kernel(const u16* __restrict__ KVraw,
                                                 u16* __restrict__ Vt) {
    int idx = blockIdx.x * 256 + threadIdx.x;
    int t = idx & (TT - 1);
    int d = (idx >> 10) & (HDIM - 1);
    int bk = idx >> 17;
    Vt[idx] = KVraw[((long)(bk >> 2) * TT + t) * 1024 + 512 + (bk & 3) * HDIM + d];
}

// ---------------------------------------------------------------------------
// Flash attention, causal, GQA.  Block = (b, h, qt): 64 q-rows, 256 threads.
// Each wave owns 16 q-rows (own online softmax). Finite masks (no inf math).
// Q (B,H,T,HD), Kr (B,KVH,T,HD), Vt (B,KVH,HD,T) -> O (B,T,H*HD)
// ---------------------------------------------------------------------------
__global__ __launch_bounds__(256) void attn_kernel(const u16* __restrict__ Q,
                                                   const u16* __restrict__ Kr,
                                                   const u16* __restrict__ Vt,
                                                   u16* __restrict__ O) {
    __shared__ alignas(16) u16 Qs[64 * 136];
    __shared__ alignas(16) u16 Ks[64 * 136];
    __shared__ alignas(16) u16 Vts[128 * 72];
    __shared__ alignas(16) u16 Ps[64 * 72];

    const int tid = threadIdx.x, w = tid >> 6, lane = tid & 63;
    const int l16 = lane & 15, quad = lane >> 4;
    const int bid = blockIdx.x;
    const int qt = 15 - (bid & 15);          // heavy tiles first
    const int bh = bid >> 4;
    const int b = bh >> 4, h = bh & 15;
    const int kvh = h >> 2;
    const long qbase = ((long)bh * TT + qt * 64) * HDIM;
    const long kbase = ((long)(b * NKV + kvh) * TT) * HDIM;
    const long vbase = ((long)(b * NKV + kvh) * HDIM) * TT;

#pragma unroll
    for (int i = 0; i < 4; i++) {
        int c = tid + i * 256;
        int row = c >> 4, cb = (c & 15) * 8;
        *(uint4*)&Qs[row * 136 + cb] = *(const uint4*)&Q[qbase + (long)row * HDIM + cb];
    }

    f32x4 o[8];
#pragma unroll
    for (int i = 0; i < 8; i++) o[i] = {0.f, 0.f, 0.f, 0.f};
    const float NEG = -1.0e30f;
    float mrow[4], lrow[4];
#pragma unroll
    for (int r = 0; r < 4; r++) { mrow[r] = NEG; lrow[r] = 0.f; }

    const float scale = 0.08838834764831845f;  // 1/sqrt(128)

    for (int kt = 0; kt <= qt; kt++) {
        __syncthreads();
#pragma unroll
        for (int i = 0; i < 4; i++) {
            int c = tid + i * 256;
            int row = c >> 4, cb = (c & 15) * 8;
            *(uint4*)&Ks[row * 136 + cb] =
                *(const uint4*)&Kr[kbase + (long)(kt * 64 + row) * HDIM + cb];
        }
#pragma unroll
        for (int i = 0; i < 4; i++) {
            int c = tid + i * 256;
            int d = c >> 3, cb = (c & 7) * 8;
            *(uint4*)&Vts[d * 72 + cb] =
                *(const uint4*)&Vt[vbase + (long)d * TT + kt * 64 + cb];
        }
        __syncthreads();

        // S = Q * K^T  (per wave: 16 q-rows x 64 k-cols)
        f32x4 s[4];
#pragma unroll
        for (int nt = 0; nt < 4; nt++) s[nt] = {0.f, 0.f, 0.f, 0.f};
#pragma unroll
        for (int ds = 0; ds < 4; ds++) {
            bf16x8 aq = *(const bf16x8*)&Qs[(w * 16 + l16) * 136 + ds * 32 + quad * 8];
#pragma unroll
            for (int nt = 0; nt < 4; nt++) {
                bf16x8 bk = *(const bf16x8*)&Ks[(nt * 16 + l16) * 136 + ds * 32 + quad * 8];
                s[nt] = __builtin_amdgcn_mfma_f32_16x16x32_bf16(aq, bk, s[nt], 0, 0, 0);
            }
        }

        // mask + online softmax (rows quad*4+r, cols nt*16+l16)
        float p[4][4], alpha[4];
#pragma unroll
        for (int r = 0; r < 4; r++) {
            int qrow = qt * 64 + w * 16 + quad * 4 + r;
            float mx = NEG;
#pragma unroll
            for (int nt = 0; nt < 4; nt++) {
                int kcol = kt * 64 + nt * 16 + l16;
                float sv = (kcol <= qrow) ? (float)s[nt][r] * scale : NEG;
                p[nt][r] = sv;
                mx = fmaxf(mx, sv);
            }
            mx = fmaxf(mx, __shfl_xor(mx, 1));
            mx = fmaxf(mx, __shfl_xor(mx, 2));
            mx = fmaxf(mx, __shfl_xor(mx, 4));
            mx = fmaxf(mx, __shfl_xor(mx, 8));
            float mnew = fmaxf(mrow[r], mx);
            alpha[r] = __expf(fmaxf(mrow[r] - mnew, -87.0f));
            if (mrow[r] <= NEG) alpha[r] = 0.f;
            float rs = 0.f;
#pragma unroll
            for (int nt = 0; nt < 4; nt++) {
                float e = (p[nt][r] <= NEG) ? 0.f : __expf(p[nt][r] - mnew);
                p[nt][r] = e;
                rs += e;
            }
            rs += __shfl_xor(rs, 1);
            rs += __shfl_xor(rs, 2);
            rs += __shfl_xor(rs, 4);
            rs += __shfl_xor(rs, 8);
            lrow[r] = lrow[r] * alpha[r] + rs;
            mrow[r] = mnew;
        }

        // P -> LDS (C-layout write), rescale O
#pragma unroll
        for (int r = 0; r < 4; r++)
#pragma unroll
            for (int nt = 0; nt < 4; nt++)
                Ps[(w * 16 + quad * 4 + r) * 72 + nt * 16 + l16] = f2b(p[nt][r]);
#pragma unroll
        for (int n8 = 0; n8 < 8; n8++)
#pragma unroll
            for (int r = 0; r < 4; r++) o[n8][r] *= alpha[r];
        __syncthreads();   // order Ps writes before A-fragment reads

        // O += P * V
#pragma unroll
        for (int ks = 0; ks < 2; ks++) {
            bf16x8 ap = *(const bf16x8*)&Ps[(w * 16 + l16) * 72 + ks * 32 + quad * 8];
#pragma unroll
            for (int n8 = 0; n8 < 8; n8++) {
                bf16x8 bv = *(const bf16x8*)&Vts[(n8 * 16 + l16) * 72 + ks * 32 + quad * 8];
                o[n8] = __builtin_amdgcn_mfma_f32_16x16x32_bf16(ap, bv, o[n8], 0, 0, 0);
            }
        }
    }

    // normalize + write O (B,T,H*HD)
#pragma unroll
    for (int n8 = 0; n8 < 8; n8++) {
#pragma unroll
        for (int r = 0; r < 4; r++) {
            int qrow = qt * 64 + w * 16 + quad * 4 + r;
            float val = o[n8][r] / lrow[r];
            O[((long)(b * TT + qrow)) * CDIM + h * HDIM + n8 * 16 + l16] = f2b(val);
        }
    }
}

// ---------------------------------------------------------------------------
extern "C" void kernel_launch(void* const* d_in, const int* in_sizes, int n_in,
                              void* d_out, int out_size, void* d_ws, size_t ws_size,
                              hipStream_t stream) {
    const void* x   = d_in[0];
    const void* Wq  = d_in[1];
    const void* Wkv = d_in[2];
    const void* Wo  = d_in[3];
    const void* cs  = d_in[4];
    const void* sn  = d_in[5];

    char* ws = (char*)d_ws;
    const size_t NEED = 105119748;
    if (ws_size < NEED) return;  // distinct failure signature (out stays 0)

    u16* WqT   = (u16*)(ws + 0);          // 2048x2048
    u16* WkvT  = (u16*)(ws + 8388608);    // 1024x2048
    u16* WoT   = (u16*)(ws + 12582912);   // 2048x2048
    u16* Qraw  = (u16*)(ws + 20971520);   // 4096x2048
    u16* KVraw = (u16*)(ws + 37748736);   // 4096x1024
    u16* Qr    = (u16*)(ws + 46137344);   // (B,H,T,HD)
    u16* Kr    = (u16*)(ws + 62914560);   // (B,KVH,T,HD)
    u16* Vt    = (u16*)(ws + 67108864);   // (B,KVH,HD,T)
    u16* ATT   = (u16*)(ws + 71303168);   // 4096x2048
    u16* xb    = (u16*)(ws + 88080384);   // 4096x2048 bf16 x
    u16* csb   = (u16*)(ws + 104857600);  // 1024x64
    u16* snb   = (u16*)(ws + 104988672);  // 1024x64
    u32* flag  = (u32*)(ws + 105119744);

    detect_k<<<1, 256, 0, stream>>>((const u16*)x, flag);

    conv_k<<<8192, 256, 0, stream>>>(x, xb, flag, 8388608);
    conv_k<<<64, 256, 0, stream>>>(cs, csb, flag, 65536);
    conv_k<<<64, 256, 0, stream>>>(sn, snb, flag, 65536);

    transpose_k<<<dim3(32, 32), 256, 0, stream>>>(Wq, WqT, 2048, 2048, flag);
    transpose_k<<<dim3(16, 32), 256, 0, stream>>>(Wkv, WkvT, 2048, 1024, flag);
    transpose_k<<<dim3(32, 32), 256, 0, stream>>>(Wo, WoT, 2048, 2048, flag);

    gemm_bt<<<dim3(16, 32), 256, 0, stream>>>(xb, WqT, Qraw, 4096, 2048, 2048, nullptr);
    gemm_bt<<<dim3(8, 32), 256, 0, stream>>>(xb, WkvT, KVraw, 4096, 1024, 2048, nullptr);

    rope_q_kernel<<<16384, 256, 0, stream>>>(Qraw, csb, snb, Qr);
    rope_k_kernel<<<4096, 256, 0, stream>>>(KVraw, csb, snb, Kr);
    vt_kernel<<<8192, 256, 0, stream>>>(KVraw, Vt);

    attn_kernel<<<1024, 256, 0, stream>>>(Qr, Kr, Vt, ATT);

    gemm_bt<<<dim3(16, 32), 256, 0, stream>>>(ATT, WoT, d_out, 4096, 2048, 2048, flag);
}

// Round 4
// 420.077 us; speedup vs baseline: 1.0595x; 1.0595x over previous
//
#include <hip/hip_runtime.h>

typedef unsigned short u16;
typedef unsigned int u32;
typedef __bf16 bf16x8 __attribute__((ext_vector_type(8)));
typedef float f32x4 __attribute__((ext_vector_type(4)));

#define BB   4
#define TT   1024
#define CDIM 2048
#define NH   16
#define NKV  4
#define HDIM 128

__device__ __forceinline__ float b2f(u16 u) {
    union { u32 i; float f; } x; x.i = ((u32)u) << 16; return x.f;
}
__device__ __forceinline__ u16 f2b(float f) {
    union { float f; u32 i; } x; x.f = f;
    u32 r = (x.i + 0x7fffu + ((x.i >> 16) & 1u)) >> 16;
    return (u16)r;
}
__device__ __forceinline__ void async16(const void* g, void* l) {
    __builtin_amdgcn_global_load_lds((const __attribute__((address_space(1))) void*)g,
                                     (__attribute__((address_space(3))) void*)l, 16, 0, 0);
}

// ---------------------------------------------------------------------------
// Dtype probe — sample EVEN u16 indices (low mantissa halves of fp32).
// ---------------------------------------------------------------------------
__global__ void detect_k(const u16* __restrict__ x, u32* __restrict__ flag) {
    __shared__ int cnt;
    if (threadIdx.x == 0) cnt = 0;
    __syncthreads();
    int bad = 0;
#pragma unroll
    for (int i = 0; i < 4; i++) {
        u16 v = x[(threadIdx.x * 4 + i) * 2];    // EVEN index
        int e = (v >> 7) & 0xFF;
        if (v != 0 && (e < 90 || e > 160)) bad++;
    }
    atomicAdd(&cnt, bad);
    __syncthreads();
    if (threadIdx.x == 0) *flag = (cnt > 100) ? 1u : 0u;
}

// Convert-or-copy to bf16, 4 elements per thread. n multiple of 1024.
__global__ __launch_bounds__(256) void conv_k(const void* __restrict__ src,
                                              u16* __restrict__ dst,
                                              const u32* __restrict__ flag, int n) {
    int i = blockIdx.x * 256 + threadIdx.x;
    if (i * 4 >= n) return;
    union { u16 u[4]; ushort4 v; } o;
    if (*flag) {
        float4 f = ((const float4*)src)[i];
        o.u[0] = f2b(f.x); o.u[1] = f2b(f.y); o.u[2] = f2b(f.z); o.u[3] = f2b(f.w);
    } else {
        o.v = ((const ushort4*)src)[i];
    }
    ((ushort4*)dst)[i] = o.v;
}

// ---------------------------------------------------------------------------
// Tiled transpose with dtype-flexible load: WT[c][r] = bf16(W[r][c]).
// ---------------------------------------------------------------------------
__global__ __launch_bounds__(256) void transpose_k(const void* __restrict__ W,
                                                   u16* __restrict__ WT,
                                                   int rows, int cols,
                                                   const u32* __restrict__ flag) {
    __shared__ alignas(16) u16 tile[64 * 65];
    const bool f32m = (*flag != 0);
    const int r0 = blockIdx.y * 64, c0 = blockIdx.x * 64;
#pragma unroll
    for (int i = 0; i < 16; i++) {
        int c = threadIdx.x + i * 256;
        int rr = c >> 6, cc = c & 63;
        long idx = (long)(r0 + rr) * cols + c0 + cc;
        tile[rr * 65 + cc] = f32m ? f2b(((const float*)W)[idx]) : ((const u16*)W)[idx];
    }
    __syncthreads();
#pragma unroll
    for (int i = 0; i < 16; i++) {
        int c = threadIdx.x + i * 256;
        int rr = c >> 6, cc = c & 63;
        WT[(long)(c0 + rr) * rows + r0 + cc] = tile[cc * 65 + rr];
    }
}

// ---------------------------------------------------------------------------
// m97-style bf16 GEMM: C[m][n] = sum_k A[m][k] * Bt[n][k].
// ---------------------------------------------------------------------------
__global__ __launch_bounds__(256) void gemm_bt(const u16* __restrict__ A,
                                               const u16* __restrict__ Bt,
                                               void* __restrict__ C,
                                               int M, int N, int Kd,
                                               const u32* __restrict__ flag) {
    __shared__ alignas(16) u16 As[128 * 32];
    __shared__ alignas(16) u16 Bs[128 * 32];
    const int tid = threadIdx.x;
    const int w = tid >> 6, lane = tid & 63;
    const int wm = w >> 1, wn = w & 1;
    const int l16 = lane & 15, quad = lane >> 4;
    const int bm = blockIdx.y, bn = blockIdx.x;
    const long arow0 = (long)bm * 128;
    const long brow0 = (long)bn * 128;
    const int srow = lane >> 2;
    const int schunk = lane & 3;

    f32x4 acc[4][4];
#pragma unroll
    for (int i = 0; i < 4; i++)
#pragma unroll
        for (int j = 0; j < 4; j++) acc[i][j] = {0.f, 0.f, 0.f, 0.f};

    for (int k0 = 0; k0 < Kd; k0 += 32) {
        __syncthreads();
#pragma unroll
        for (int j = 0; j < 2; j++) {
            int r0 = w * 32 + j * 16;
            const u16* gA = A + (arow0 + r0 + srow) * Kd + k0 + schunk * 8;
            async16(gA, &As[r0 * 32]);
            const u16* gB = Bt + (brow0 + r0 + srow) * Kd + k0 + schunk * 8;
            async16(gB, &Bs[r0 * 32]);
        }
        __syncthreads();
        bf16x8 af[4], bfr[4];
#pragma unroll
        for (int mt = 0; mt < 4; mt++)
            af[mt] = *(const bf16x8*)&As[(wm * 64 + mt * 16 + l16) * 32 + quad * 8];
#pragma unroll
        for (int nt = 0; nt < 4; nt++)
            bfr[nt] = *(const bf16x8*)&Bs[(wn * 64 + nt * 16 + l16) * 32 + quad * 8];
#pragma unroll
        for (int mt = 0; mt < 4; mt++)
#pragma unroll
            for (int nt = 0; nt < 4; nt++)
                acc[mt][nt] = __builtin_amdgcn_mfma_f32_16x16x32_bf16(
                    af[mt], bfr[nt], acc[mt][nt], 0, 0, 0);
    }
    const bool f32m = (flag != nullptr) && (*flag != 0);
#pragma unroll
    for (int mt = 0; mt < 4; mt++) {
#pragma unroll
        for (int nt = 0; nt < 4; nt++) {
            int col = bn * 128 + wn * 64 + nt * 16 + l16;
#pragma unroll
            for (int r = 0; r < 4; r++) {
                long row = bm * 128 + wm * 64 + mt * 16 + quad * 4 + r;
                if (f32m) ((float*)C)[row * N + col] = acc[mt][nt][r];
                else      ((u16*)C)[row * N + col] = f2b(acc[mt][nt][r]);
            }
        }
    }
}

// ---------------------------------------------------------------------------
// RoPE on Q: Qraw (B*T, 2048) -> Q (B,H,T,HD)
// ---------------------------------------------------------------------------
__global__ __launch_bounds__(256) void rope_q_kernel(const u16* __restrict__ Qraw,
                                                     const u16* __restrict__ cs,
                                                     const u16* __restrict__ sn,
                                                     u16* __restrict__ Q) {
    int idx = blockIdx.x * 256 + threadIdx.x;
    int d = idx & 63;
    int t = (idx >> 6) & (TT - 1);
    int bh = idx >> 16;
    long src = ((long)((bh >> 4) * TT + t)) * CDIM + (bh & 15) * HDIM;
    float u1 = b2f(Qraw[src + d]), u2 = b2f(Qraw[src + d + 64]);
    float c = b2f(cs[t * 64 + d]), s = b2f(sn[t * 64 + d]);
    long dst = ((long)bh * TT + t) * HDIM;
    Q[dst + d] = f2b(u1 * c - u2 * s);
    Q[dst + d + 64] = f2b(u1 * s + u2 * c);
}

// RoPE on K: KVraw (B*T, 1024) -> K (B,KVH,T,HD)
__global__ __launch_bounds__(256) void rope_k_kernel(const u16* __restrict__ KVraw,
                                                     const u16* __restrict__ cs,
                                                     const u16* __restrict__ sn,
                                                     u16* __restrict__ K) {
    int idx = blockIdx.x * 256 + threadIdx.x;
    int d = idx & 63;
    int t = (idx >> 6) & (TT - 1);
    int bk = idx >> 16;
    long src = ((long)((bk >> 2) * TT + t)) * 1024 + (bk & 3) * HDIM;
    float u1 = b2f(KVraw[src + d]), u2 = b2f(KVraw[src + d + 64]);
    float c = b2f(cs[t * 64 + d]), s = b2f(sn[t * 64 + d]);
    long dst = ((long)bk * TT + t) * HDIM;
    K[dst + d] = f2b(u1 * c - u2 * s);
    K[dst + d + 64] = f2b(u1 * s + u2 * c);
}

// V rearrange: KVraw -> Vt (B,KVH,HD,T)
__global__ __launch_bounds__(256) void vt_kernel(const u16* __restrict__ KVraw,
                                                 u16* __restrict__ Vt) {
    int idx = blockIdx.x * 256 + threadIdx.x;
    int t = idx & (TT - 1);
    int d = (idx >> 10) & (HDIM - 1);
    int bk = idx >> 17;
    Vt[idx] = KVraw[((long)(bk >> 2) * TT + t) * 1024 + 512 + (bk & 3) * HDIM + d];
}

// ---------------------------------------------------------------------------
// Flash attention v2 — S^T formulation.
// Block = (b,h,qt): 64 q-rows, 4 waves, each wave owns 16 q (= its l16 lanes).
// S^T = K·Q^T so a q-row's k-values live in one lane column: softmax needs
// only 4 shuffles/iter; m/l are scalar per lane; O^T = V^T·P^T with P staged
// per-wave through LDS (packed u32 writes, b128 read, no barrier).
// Staging via global_load_lds + XOR chunk swizzle (async-compatible AND
// <=2-way bank conflicts on fragment reads).
// ---------------------------------------------------------------------------
__global__ __launch_bounds__(256) void attn_kernel(const u16* __restrict__ Q,
                                                   const u16* __restrict__ Kr,
                                                   const u16* __restrict__ Vt,
                                                   u16* __restrict__ O) {
    __shared__ alignas(16) u16 Qs[64 * 128];   // [q][d], chunk^=(row&7), keep bit3
    __shared__ alignas(16) u16 Ks[64 * 128];   // [t][d], same swizzle
    __shared__ alignas(16) u16 Vts[128 * 64];  // [d][t], chunk^=(row&7)
    __shared__ alignas(16) u16 Ps[64 * 88];    // [q][k], stride 88 (44 dw)

    const int tid = threadIdx.x, w = tid >> 6, lane = tid & 63;
    const int l16 = lane & 15, quad = lane >> 4;
    const int bid = blockIdx.x;
    const int qt = 15 - (bid & 15);          // heavy tiles first
    const int bh = bid >> 4;
    const int b = bh >> 4, h = bh & 15;
    const int kvh = h >> 2;
    const long qrow0 = (long)bh * TT + qt * 64;            // row into Q
    const long krow0 = (long)(b * NKV + kvh) * TT;         // row into Kr
    const long vbase = ((long)(b * NKV + kvh) * HDIM) * TT;

    // Stage Q tile (64 rows x 16 chunks), swizzled
#pragma unroll
    for (int i = 0; i < 4; i++) {
        int slot0 = (w * 4 + i) * 64;
        int slot = slot0 + lane;
        int row = slot >> 4, cp = slot & 15;
        int cg = (cp & 8) | ((cp ^ row) & 7);
        async16(Q + (qrow0 + row) * HDIM + cg * 8, &Qs[slot0 * 8]);
    }

    f32x4 o[8];
#pragma unroll
    for (int i = 0; i < 8; i++) o[i] = {0.f, 0.f, 0.f, 0.f};
    float m_i = -1.0e30f, l_i = 0.f;
    const int qg = qt * 64 + w * 16 + l16;   // this lane's q (t-index in head)
    const float scale = 0.08838834764831845f;  // 1/sqrt(128)

    for (int kt = 0; kt <= qt; kt++) {
        __syncthreads();
        // Stage K tile (64 rows x 16 chunks) + V^T tile (128 rows x 8 chunks)
#pragma unroll
        for (int i = 0; i < 4; i++) {
            int slot0 = (w * 4 + i) * 64;
            int slot = slot0 + lane;
            int row = slot >> 4, cp = slot & 15;
            int cg = (cp & 8) | ((cp ^ row) & 7);
            async16(Kr + (krow0 + kt * 64 + row) * HDIM + cg * 8, &Ks[slot0 * 8]);
        }
#pragma unroll
        for (int i = 0; i < 4; i++) {
            int slot0 = (w * 4 + i) * 64;
            int slot = slot0 + lane;
            int row = slot >> 3, cp = slot & 7;
            int cg = cp ^ (row & 7);
            async16(Vt + vbase + (long)row * TT + kt * 64 + cg * 8, &Vts[slot0 * 8]);
        }
        __syncthreads();

        // S^T[kcol][q] = sum_d K[kcol][d] * Q[q][d]
        f32x4 s[4];
#pragma unroll
        for (int nt = 0; nt < 4; nt++) s[nt] = {0.f, 0.f, 0.f, 0.f};
#pragma unroll
        for (int ds = 0; ds < 4; ds++) {
            int Rq = w * 16 + l16;
            int c = ds * 4 + quad;
            bf16x8 bq = *(const bf16x8*)&Qs[Rq * 128 + ((c & 8) | ((c ^ Rq) & 7)) * 8];
#pragma unroll
            for (int nt = 0; nt < 4; nt++) {
                int Rk = nt * 16 + l16;
                bf16x8 ak = *(const bf16x8*)&Ks[Rk * 128 + ((c & 8) | ((c ^ Rk) & 7)) * 8];
                s[nt] = __builtin_amdgcn_mfma_f32_16x16x32_bf16(ak, bq, s[nt], 0, 0, 0);
            }
        }

        // online softmax over this lane's 16 k-values + cross-quad reduce
        float p[4][4];
        float mx = -1.0e30f;
        if (kt == qt) {
#pragma unroll
            for (int nt = 0; nt < 4; nt++)
#pragma unroll
                for (int r = 0; r < 4; r++) {
                    int kcol = kt * 64 + nt * 16 + quad * 4 + r;
                    float v = (kcol <= qg) ? (float)s[nt][r] * scale : -1.0e30f;
                    p[nt][r] = v;
                    mx = fmaxf(mx, v);
                }
        } else {
#pragma unroll
            for (int nt = 0; nt < 4; nt++)
#pragma unroll
                for (int r = 0; r < 4; r++) {
                    float v = (float)s[nt][r] * scale;
                    p[nt][r] = v;
                    mx = fmaxf(mx, v);
                }
        }
        mx = fmaxf(mx, __shfl_xor(mx, 16));
        mx = fmaxf(mx, __shfl_xor(mx, 32));
        float mnew = fmaxf(m_i, mx);
        float alpha = __expf(m_i - mnew);
        float rs = 0.f;
#pragma unroll
        for (int nt = 0; nt < 4; nt++)
#pragma unroll
            for (int r = 0; r < 4; r++) {
                float e = __expf(p[nt][r] - mnew);
                p[nt][r] = e;
                rs += e;
            }
        rs += __shfl_xor(rs, 16);
        rs += __shfl_xor(rs, 32);
        l_i = l_i * alpha + rs;
        m_i = mnew;

        // P[q][k] -> Ps (packed u32, per-wave rows only)
        u32* Psw = (u32*)Ps;
        int pb = (w * 16 + l16) * 44 + quad * 2;
#pragma unroll
        for (int nt = 0; nt < 4; nt++) {
            u32 lo = (u32)f2b(p[nt][0]) | ((u32)f2b(p[nt][1]) << 16);
            u32 hi = (u32)f2b(p[nt][2]) | ((u32)f2b(p[nt][3]) << 16);
            Psw[pb + nt * 8]     = lo;
            Psw[pb + nt * 8 + 1] = hi;
        }
        // rescale O (alpha is lane-uniform)
#pragma unroll
        for (int n8 = 0; n8 < 8; n8++)
#pragma unroll
            for (int r = 0; r < 4; r++) o[n8][r] *= alpha;

        asm volatile("s_waitcnt lgkmcnt(0)" ::: "memory");  // order Ps W->R (same wave)

        // O^T[d][q] += sum_k V^T[d][k] * P[q][k]
#pragma unroll
        for (int ks = 0; ks < 2; ks++) {
            bf16x8 bp = *(const bf16x8*)&Ps[(w * 16 + l16) * 88 + ks * 32 + quad * 8];
#pragma unroll
            for (int n8 = 0; n8 < 8; n8++) {
                int Rv = n8 * 16 + l16;
                int c = ks * 4 + quad;
                bf16x8 av = *(const bf16x8*)&Vts[Rv * 64 + (c ^ (Rv & 7)) * 8];
                o[n8] = __builtin_amdgcn_mfma_f32_16x16x32_bf16(av, bp, o[n8], 0, 0, 0);
            }
        }
    }

    // epilogue: normalize, pack 4 bf16, store (row = lane's q; cols d-contig)
    float inv = 1.0f / l_i;
    long obase = ((long)(b * TT + qg)) * CDIM + h * HDIM;
#pragma unroll
    for (int n8 = 0; n8 < 8; n8++) {
        ushort4 st;
        st.x = f2b(o[n8][0] * inv);
        st.y = f2b(o[n8][1] * inv);
        st.z = f2b(o[n8][2] * inv);
        st.w = f2b(o[n8][3] * inv);
        *(ushort4*)&O[obase + n8 * 16 + quad * 4] = st;
    }
}

// ---------------------------------------------------------------------------
extern "C" void kernel_launch(void* const* d_in, const int* in_sizes, int n_in,
                              void* d_out, int out_size, void* d_ws, size_t ws_size,
                              hipStream_t stream) {
    const void* x   = d_in[0];
    const void* Wq  = d_in[1];
    const void* Wkv = d_in[2];
    const void* Wo  = d_in[3];
    const void* cs  = d_in[4];
    const void* sn  = d_in[5];

    char* ws = (char*)d_ws;
    const size_t NEED = 105119748;
    if (ws_size < NEED) return;

    u16* WqT   = (u16*)(ws + 0);          // 2048x2048
    u16* WkvT  = (u16*)(ws + 8388608);    // 1024x2048
    u16* WoT   = (u16*)(ws + 12582912);   // 2048x2048
    u16* Qraw  = (u16*)(ws + 20971520);   // 4096x2048
    u16* KVraw = (u16*)(ws + 37748736);   // 4096x1024
    u16* Qr    = (u16*)(ws + 46137344);   // (B,H,T,HD)
    u16* Kr    = (u16*)(ws + 62914560);   // (B,KVH,T,HD)
    u16* Vt    = (u16*)(ws + 67108864);   // (B,KVH,HD,T)
    u16* ATT   = (u16*)(ws + 71303168);   // 4096x2048
    u16* xb    = (u16*)(ws + 88080384);   // 4096x2048 bf16 x
    u16* csb   = (u16*)(ws + 104857600);  // 1024x64
    u16* snb   = (u16*)(ws + 104988672);  // 1024x64
    u32* flag  = (u32*)(ws + 105119744);

    detect_k<<<1, 256, 0, stream>>>((const u16*)x, flag);

    conv_k<<<8192, 256, 0, stream>>>(x, xb, flag, 8388608);
    conv_k<<<64, 256, 0, stream>>>(cs, csb, flag, 65536);
    conv_k<<<64, 256, 0, stream>>>(sn, snb, flag, 65536);

    transpose_k<<<dim3(32, 32), 256, 0, stream>>>(Wq, WqT, 2048, 2048, flag);
    transpose_k<<<dim3(16, 32), 256, 0, stream>>>(Wkv, WkvT, 2048, 1024, flag);
    transpose_k<<<dim3(32, 32), 256, 0, stream>>>(Wo, WoT, 2048, 2048, flag);

    gemm_bt<<<dim3(16, 32), 256, 0, stream>>>(xb, WqT, Qraw, 4096, 2048, 2048, nullptr);
    gemm_bt<<<dim3(8, 32), 256, 0, stream>>>(xb, WkvT, KVraw, 4096, 1024, 2048, nullptr);

    rope_q_kernel<<<16384, 256, 0, stream>>>(Qraw, csb, snb, Qr);
    rope_k_kernel<<<4096, 256, 0, stream>>>(KVraw, csb, snb, Kr);
    vt_kernel<<<8192, 256, 0, stream>>>(KVraw, Vt);

    attn_kernel<<<1024, 256, 0, stream>>>(Qr, Kr, Vt, ATT);

    gemm_bt<<<dim3(16, 32), 256, 0, stream>>>(ATT, WoT, d_out, 4096, 2048, 2048, flag);
}